// Round 14
// baseline (279.539 us; speedup 1.0000x reference)
//
#include <hip/hip_runtime.h>

#define WW 1024
#define HH 1024
#define BB 16
#define HWSZ (HH * WW)
#define NBLK (BB * HH)

typedef float f32x4 __attribute__((ext_vector_type(4)));

// Program-order-pinned 16B global load (volatile asm chain -> no compiler
// waitcnt between loads, all outstanding together).
#define GLOAD(dst, ptr) \
    asm volatile("global_load_dwordx4 %0, %1, off" : "=v"(dst) : "v"(ptr))

// Async global->LDS DMA: no VGPR destination, so regalloc cannot serialize
// it. Per-lane global src; wave-uniform LDS base (lane l writes base+16*l).
#define GLOAD_LDS(gsrc, ldst)                                                  \
    __builtin_amdgcn_global_load_lds(                                          \
        (const __attribute__((address_space(1))) void*)(gsrc),                 \
        (__attribute__((address_space(3))) void*)(ldst), 16, 0, 0)

// ---------------------------------------------------------------------------
// D2(f) = gradient(gradient(f)) along one axis (jnp.gradient semantics):
//   i=0:      (f0 - 2 f1 + f2)/2
//   i=1:      (2 f0 - 3 f1 + f3)/4
//   interior: (f[i-2] - 2 f[i] + f[i+2])/4
//   i=N-2:    (f[N-4] - 3 f[N-2] + 2 f[N-1])/4
//   i=N-1:    (f[N-3] - 2 f[N-2] + f[N-1])/2
// ---------------------------------------------------------------------------

__device__ __forceinline__ void vert_cfg(int h, int& rA, int& rB,
                                         float& cA, float& cB, float& ch) {
    if (h == 0)            { rA = 1;      rB = 2;      cA = -1.0f;  cB = 0.5f;   ch = 0.5f;   }
    else if (h == 1)       { rA = 0;      rB = 3;      cA = 0.5f;   cB = 0.25f;  ch = -0.75f; }
    else if (h == HH - 2)  { rA = HH - 4; rB = HH - 1; cA = 0.25f;  cB = 0.5f;   ch = -0.75f; }
    else if (h == HH - 1)  { rA = HH - 3; rB = HH - 2; cA = 0.5f;   cB = -1.0f;  ch = 0.5f;   }
    else                   { rA = h - 2;  rB = h + 2;  cA = 0.25f;  cB = 0.25f;  ch = -0.5f;  }
}

__device__ __forceinline__ void lap_compute(const f32x4 vh, const f32x4 vhp,
                                            const f32x4 vhn, const f32x4 vA,
                                            const f32x4 vB, int g,
                                            float cA, float cB, float ch,
                                            float out[4]) {
    float vert[4];
    vert[0] = cA * vA.x + cB * vB.x + ch * vh.x;
    vert[1] = cA * vA.y + cB * vB.y + ch * vh.y;
    vert[2] = cA * vA.z + cB * vB.z + ch * vh.z;
    vert[3] = cA * vA.w + cB * vB.w + ch * vh.w;

    float win[8] = {vhp.z, vhp.w, vh.x, vh.y, vh.z, vh.w, vhn.x, vhn.y};
    float hz[4];
#pragma unroll
    for (int p = 0; p < 4; ++p)
        hz[p] = 0.25f * (win[p] - 2.0f * win[p + 2] + win[p + 4]);

    if (g == 0) {                         // columns 0,1
        hz[0] = 0.5f  * (vh.x - 2.0f * vh.y + vh.z);
        hz[1] = 0.25f * (2.0f * vh.x - 3.0f * vh.y + vh.w);
    } else if (g == WW / 4 - 1) {         // columns W-2, W-1
        hz[2] = 0.25f * (vh.x - 3.0f * vh.z + 2.0f * vh.w);
        hz[3] = 0.5f  * (vh.y - 2.0f * vh.z + vh.w);
    }

#pragma unroll
    for (int p = 0; p < 4; ++p) out[p] = vert[p] + hz[p];
}

// Shared epilogue: psi term + per-block reduction + partial write.
template <int USE_ATOMIC>
__device__ __forceinline__ void epilogue(const float lapx[4], const float lapy[4],
                                         const f32x4 r4, const f32x4 i4,
                                         double* part, int pidx) {
    const float rr[4] = {r4.x, r4.y, r4.z, r4.w};
    const float ii[4] = {i4.x, i4.y, i4.z, i4.w};
    float s = 0.0f;
#pragma unroll
    for (int p = 0; p < 4; ++p) {
        const float c   = 1.0f - (rr[p] * rr[p] + ii[p] * ii[p]);   // 1/eps^2 = 1
        const float lap = lapx[p] + lapy[p];
        const float re  = lap + c * rr[p];
        const float im  = c * ii[p];
        s += re * re + im * im;
    }
#pragma unroll
    for (int off = 32; off > 0; off >>= 1) s += __shfl_down(s, off);

    __shared__ float wsum[4];
    const int lane = threadIdx.x & 63;
    const int wv   = threadIdx.x >> 6;
    if (lane == 0) wsum[wv] = s;
    __syncthreads();
    if (threadIdx.x == 0) {
        const double t = (double)(wsum[0] + wsum[1]) + (double)(wsum[2] + wsum[3]);
        if (USE_ATOMIC) atomicAdd(part, t);
        else            part[pidx] = t;
    }
}

// Variants A/B: register loads. USE_ASM=1 -> asm-pinned cluster.
template <int USE_ATOMIC, int USE_ASM, int B_BASE, int PBASE>
__global__ __launch_bounds__(256, 2) void gl2_main(const float* __restrict__ u,
                                                   const float* __restrict__ psi,
                                                   double* __restrict__ part) {
    const int bid  = blockIdx.x;
    const int work = (bid & 7) * ((int)gridDim.x >> 3) + (bid >> 3);
    const int b = B_BASE + (work >> 10);
    const int h = work & 1023;
    const int g = threadIdx.x;

    int rA, rB; float cA, cB, ch;
    vert_cfg(h, rA, rB, cA, cB, ch);

    const float* ux = u   + ((size_t)b * 2 + 0) * HWSZ;
    const float* uy = u   + ((size_t)b * 2 + 1) * HWSZ;
    const float* pr = psi + ((size_t)b * 2 + 0) * HWSZ;
    const float* pi = psi + ((size_t)b * 2 + 1) * HWSZ;

    const int gp = (g > 0) ? g - 1 : g;
    const int gn = (g < WW / 4 - 1) ? g + 1 : g;

    const f32x4* xrh = (const f32x4*)(ux + (size_t)h * WW);
    const f32x4* yrh = (const f32x4*)(uy + (size_t)h * WW);
    const f32x4* xrA = (const f32x4*)(ux + (size_t)rA * WW);
    const f32x4* xrB = (const f32x4*)(ux + (size_t)rB * WW);
    const f32x4* yrA = (const f32x4*)(uy + (size_t)rA * WW);
    const f32x4* yrB = (const f32x4*)(uy + (size_t)rB * WW);
    const f32x4* prh = (const f32x4*)(pr + (size_t)h * WW);
    const f32x4* pih = (const f32x4*)(pi + (size_t)h * WW);

    f32x4 xh, xp, xn, xA, xB, yh, yp, yn, yA, yB, r4, i4;
    if (USE_ASM) {
        GLOAD(xh, xrh + g);  GLOAD(xp, xrh + gp); GLOAD(xn, xrh + gn);
        GLOAD(xA, xrA + g);  GLOAD(xB, xrB + g);
        GLOAD(yh, yrh + g);  GLOAD(yp, yrh + gp); GLOAD(yn, yrh + gn);
        GLOAD(yA, yrA + g);  GLOAD(yB, yrB + g);
        GLOAD(r4, prh + g);  GLOAD(i4, pih + g);
        asm volatile("s_waitcnt vmcnt(0)"
                     : "+v"(xh), "+v"(xp), "+v"(xn), "+v"(xA), "+v"(xB),
                       "+v"(yh), "+v"(yp), "+v"(yn), "+v"(yA), "+v"(yB),
                       "+v"(r4), "+v"(i4));
        __builtin_amdgcn_sched_barrier(0);
    } else {
        xh = xrh[g]; xp = xrh[gp]; xn = xrh[gn];
        xA = xrA[g]; xB = xrB[g];
        yh = yrh[g]; yp = yrh[gp]; yn = yrh[gn];
        yA = yrA[g]; yB = yrB[g];
        r4 = prh[g]; i4 = pih[g];
    }

    float lapx[4], lapy[4];
    lap_compute(xh, xp, xn, xA, xB, g, cA, cB, ch, lapx);
    lap_compute(yh, yp, yn, yA, yB, g, cA, cB, ch, lapy);
    epilogue<USE_ATOMIC>(lapx, lapy, r4, i4, part, PBASE + bid);
}

// Variant C: async global->LDS staging (no VGPR dests -> nothing for
// regalloc to serialize). 8 rows x 4KB = 32KB LDS/block.
template <int USE_ATOMIC, int B_BASE, int PBASE>
__global__ __launch_bounds__(256) void gl2_lds(const float* __restrict__ u,
                                               const float* __restrict__ psi,
                                               double* __restrict__ part) {
    const int bid  = blockIdx.x;
    const int work = (bid & 7) * ((int)gridDim.x >> 3) + (bid >> 3);
    const int b = B_BASE + (work >> 10);
    const int h = work & 1023;
    const int t = threadIdx.x;

    int rA, rB; float cA, cB, ch;
    vert_cfg(h, rA, rB, cA, cB, ch);

    const float* ux = u   + ((size_t)b * 2 + 0) * HWSZ;
    const float* uy = u   + ((size_t)b * 2 + 1) * HWSZ;
    const float* pr = psi + ((size_t)b * 2 + 0) * HWSZ;
    const float* pi = psi + ((size_t)b * 2 + 1) * HWSZ;

    __shared__ float lds[8][WW];
    const float* rows[8] = { ux + (size_t)h * WW, ux + (size_t)rA * WW, ux + (size_t)rB * WW,
                             uy + (size_t)h * WW, uy + (size_t)rA * WW, uy + (size_t)rB * WW,
                             pr + (size_t)h * WW, pi + (size_t)h * WW };

    // wave w stages quarter w of each row: lane l -> lds[s][w*256 + 4l]
    const int wv = t >> 6;
#pragma unroll
    for (int s = 0; s < 8; ++s)
        GLOAD_LDS(rows[s] + (size_t)t * 4, &lds[s][wv * 256]);
    __syncthreads();   // compiler drains vmcnt before s_barrier

    const int g  = t;
    const int gp = (g > 0) ? g - 1 : g;
    const int gn = (g < WW / 4 - 1) ? g + 1 : g;

    const f32x4* L0 = (const f32x4*)lds[0];
    const f32x4* L1 = (const f32x4*)lds[1];
    const f32x4* L2 = (const f32x4*)lds[2];
    const f32x4* L3 = (const f32x4*)lds[3];
    const f32x4* L4 = (const f32x4*)lds[4];
    const f32x4* L5 = (const f32x4*)lds[5];
    const f32x4* L6 = (const f32x4*)lds[6];
    const f32x4* L7 = (const f32x4*)lds[7];

    float lapx[4], lapy[4];
    lap_compute(L0[g], L0[gp], L0[gn], L1[g], L2[g], g, cA, cB, ch, lapx);
    lap_compute(L3[g], L3[gp], L3[gn], L4[g], L5[g], g, cA, cB, ch, lapy);
    epilogue<USE_ATOMIC>(lapx, lapy, L6[g], L7[g], part, PBASE + bid);
}

__global__ void gl2_zero_acc(double* acc) {
    if (threadIdx.x == 0) acc[0] = 0.0;
}

template <int FROM_PARTIALS>
__global__ __launch_bounds__(1024) void gl2_finalize(const double* __restrict__ part,
                                                     float* __restrict__ out) {
    double s = 0.0;
    if (FROM_PARTIALS) {
#pragma unroll
        for (int k = 0; k < NBLK / 1024; ++k)
            s += part[threadIdx.x + k * 1024];
    } else {
        s = (threadIdx.x == 0) ? part[0] : 0.0;
    }
#pragma unroll
    for (int off = 32; off > 0; off >>= 1)
        s += __shfl_down(s, off);

    __shared__ double wsum[16];
    const int lane = threadIdx.x & 63;
    const int wv   = threadIdx.x >> 6;
    if (lane == 0) wsum[wv] = s;
    __syncthreads();
    if (threadIdx.x == 0) {
        double t = 0.0;
#pragma unroll
        for (int w = 0; w < 16; ++w) t += wsum[w];
        out[0] = (float)(t / (double)((size_t)BB * HWSZ));
    }
}

extern "C" void kernel_launch(void* const* d_in, const int* in_sizes, int n_in,
                              void* d_out, int out_size, void* d_ws, size_t ws_size,
                              hipStream_t stream) {
    const float* u   = (const float*)d_in[0];
    const float* psi = (const float*)d_in[1];
    float* out   = (float*)d_out;
    double* ws   = (double*)d_ws;

    // ws_size constant across calls -> branch is graph-capture safe.
    if (ws_size >= NBLK * sizeof(double)) {
        // A: asm+bounds (batches 0-3), B: plain+bounds (4-7), C: LDS (8-15)
        gl2_main<0, 1, 0, 0>      <<<4 * HH, 256, 0, stream>>>(u, psi, ws);
        gl2_main<0, 0, 4, 4 * HH> <<<4 * HH, 256, 0, stream>>>(u, psi, ws);
        gl2_lds <0, 8, 8 * HH>    <<<8 * HH, 256, 0, stream>>>(u, psi, ws);
        gl2_finalize<1><<<1, 1024, 0, stream>>>(ws, out);
    } else {
        gl2_zero_acc<<<1, 64, 0, stream>>>(ws);
        gl2_main<1, 1, 0, 0><<<4 * HH, 256, 0, stream>>>(u, psi, ws);
        gl2_main<1, 0, 4, 0><<<4 * HH, 256, 0, stream>>>(u, psi, ws);
        gl2_lds <1, 8, 0>   <<<8 * HH, 256, 0, stream>>>(u, psi, ws);
        gl2_finalize<0><<<1, 1024, 0, stream>>>(ws, out);
    }
}